// Round 1
// baseline (366.415 us; speedup 1.0000x reference)
//
#include <hip/hip_runtime.h>
#include <stdint.h>

// Problem constants
#define B_     16
#define N_     512
#define R_     10
#define DE_    256
#define DR_    64
#define DOUT_  256
#define INDIM_ 3200   // (DE+DR)*R
#define BLK_   320    // DE+DR

typedef __bf16          v8bf  __attribute__((ext_vector_type(8)));
typedef unsigned short  v8us  __attribute__((ext_vector_type(8)));
typedef float           f32x4 __attribute__((ext_vector_type(4)));

static __device__ __forceinline__ unsigned short f2b(float f) {
  union { float f; unsigned u; } c; c.f = f;
  unsigned r = c.u + 0x7FFFu + ((c.u >> 16) & 1u);   // RNE
  return (unsigned short)(r >> 16);
}

static __device__ __forceinline__ v8bf us2bf(v8us u) {
  union { v8us u; v8bf b; } c; c.u = u; return c.b;
}

// async global->LDS, 16B per lane; LDS dest = wave-uniform base + lane*16
static __device__ __forceinline__ void gl_lds16(const void* g, void* l) {
  __builtin_amdgcn_global_load_lds(
      (const __attribute__((address_space(1))) void*)g,
      (__attribute__((address_space(3))) void*)l, 16, 0, 0);
}

// ---------------- prep: node [b][m][d] f32 -> nodeT [b][d][m] bf16 -------------
__global__ void prep_nodeT(const float* __restrict__ nf, unsigned short* __restrict__ nodeT) {
  __shared__ float t[32][33];
  const int b = blockIdx.x, m0 = blockIdx.y * 32, d0 = blockIdx.z * 32;
  const int tid = threadIdx.x;
  const int c = tid & 31, rr = tid >> 5;
#pragma unroll
  for (int i = 0; i < 4; ++i) {
    int m = rr + i * 8;
    t[m][c] = nf[((size_t)b * N_ + (m0 + m)) * DE_ + d0 + c];
  }
  __syncthreads();
#pragma unroll
  for (int i = 0; i < 4; ++i) {
    int d = rr + i * 8;
    nodeT[((size_t)b * DE_ + (d0 + d)) * N_ + m0 + c] = f2b(t[c][d]);
  }
}

// ---------------- prep: W -> Wn [r][o][d] bf16 (node-part slice, d contiguous) --
__global__ void prep_W(const float* __restrict__ W, unsigned short* __restrict__ Wn) {
  int idx = blockIdx.x * 256 + threadIdx.x;        // < R*DOUT*DE = 655360
  int r = idx >> 16;                                // / (DOUT*DE)
  int o = (idx >> 8) & 255;
  int d = idx & 255;
  Wn[idx] = f2b(W[(size_t)o * INDIM_ + r * BLK_ + d]);
}

// ---------------- prep: U_bf [b][o][kk] = sum_dr rel[b,kk,dr]*W[o, kk*320+256+dr]
__global__ void prep_U(const float* __restrict__ rel, const float* __restrict__ W,
                       unsigned short* __restrict__ Ub) {
  int idx = blockIdx.x * 256 + threadIdx.x;        // < B*DOUT*64 = 262144
  int kk = idx & 63;
  int o  = (idx >> 6) & 255;
  int b  = idx >> 14;
  float v = 0.f;
  if (kk < R_) {
    const float* rp = rel + ((size_t)b * R_ + kk) * DR_;
    const float* wp = W + (size_t)o * INDIM_ + kk * BLK_ + DE_;
#pragma unroll 8
    for (int d = 0; d < DR_; ++d) v += rp[d] * wp[d];
  }
  Ub[idx] = f2b(v);
}

// ---------------- prep: spad [b][n][kk] = bf16(s[b][kk][n]) (kk<R else 0) -------
__global__ void prep_spad(const float* __restrict__ s, unsigned short* __restrict__ spad) {
  int idx = blockIdx.x * 256 + threadIdx.x;        // < B*N*64 = 524288
  int kk = idx & 63;
  int n  = (idx >> 6) & 511;
  int b  = idx >> 15;
  float v = (kk < R_) ? s[((size_t)b * R_ + kk) * N_ + n] : 0.f;
  spad[idx] = f2b(v);
}

// ---------------- stage 1: P[b,r] = adj[b,r] @ node[b]; s = rowsum(adj) --------
// 128x128 tile, BK=64, 4 waves 2x2 (64x64 each). A = adj fp32->bf16 inline,
// B = nodeT bf16 via global_load_lds. XOR chunk swizzle on both LDS tiles.
__global__ void stage1_gemm(const float* __restrict__ adj,
                            const unsigned short* __restrict__ nodeT,
                            unsigned short* __restrict__ P,
                            float* __restrict__ s) {
  __shared__ unsigned short Al[128 * 64];
  __shared__ unsigned short Bl[128 * 64];
  const int br = blockIdx.x;           // b*R + r
  const int b  = br / R_;
  const int n0 = blockIdx.y * 128;
  const int d0 = blockIdx.z * 128;
  const int tid  = threadIdx.x;
  const int lane = tid & 63;
  const int wave = tid >> 6;
  const int wm = wave >> 1, wn = wave & 1;
  const int quad = lane >> 4, l16 = lane & 15;

  const float* adjb = adj + (size_t)br * (N_ * N_);
  const unsigned short* nodeTb = nodeT + (size_t)b * (DE_ * N_);

  f32x4 acc[4][4];
#pragma unroll
  for (int i = 0; i < 4; ++i)
#pragma unroll
    for (int j = 0; j < 4; ++j) acc[i][j] = f32x4{0.f, 0.f, 0.f, 0.f};

  const int arow = tid >> 1, ahalf = tid & 1;     // A staging: 2 threads/row
  const bool do_sum = (blockIdx.z == 0);
  float rowsum = 0.f;

  for (int k0 = 0; k0 < N_; k0 += 64) {
    // B tile: nodeT rows d0..d0+127, cols k0..k0+63 (async, swizzled slots)
#pragma unroll
    for (int it = 0; it < 4; ++it) {
      int rowblk = it * 32 + wave * 8;            // wave-uniform
      int rl = rowblk + (lane >> 3);
      int kc = (lane & 7) ^ (rl & 7);             // logical chunk for my slot
      gl_lds16(nodeTb + (size_t)(d0 + rl) * N_ + k0 + kc * 8, Bl + rowblk * 64);
    }
    // A tile: adj rows n0..n0+127 fp32 -> bf16, rowsum on the side
    const float* ga = adjb + (size_t)(n0 + arow) * N_ + k0 + ahalf * 32;
#pragma unroll
    for (int c = 0; c < 4; ++c) {
      float4 x = *(const float4*)(ga + c * 8);
      float4 y = *(const float4*)(ga + c * 8 + 4);
      if (do_sum) rowsum += (x.x + x.y + x.z + x.w) + (y.x + y.y + y.z + y.w);
      v8us u;
      u[0] = f2b(x.x); u[1] = f2b(x.y); u[2] = f2b(x.z); u[3] = f2b(x.w);
      u[4] = f2b(y.x); u[5] = f2b(y.y); u[6] = f2b(y.z); u[7] = f2b(y.w);
      int cs = (ahalf * 4 + c) ^ (arow & 7);
      *(v8us*)(Al + arow * 64 + cs * 8) = u;
    }
    __syncthreads();
#pragma unroll
    for (int ks = 0; ks < 2; ++ks) {
      const int kb = ks * 4;
      v8bf av[4], bv[4];
#pragma unroll
      for (int mi = 0; mi < 4; ++mi) {
        int m = wm * 64 + mi * 16 + l16;
        av[mi] = us2bf(*(const v8us*)(Al + m * 64 + (((kb + quad) ^ (m & 7)) * 8)));
      }
#pragma unroll
      for (int ni = 0; ni < 4; ++ni) {
        int d = wn * 64 + ni * 16 + l16;
        bv[ni] = us2bf(*(const v8us*)(Bl + d * 64 + (((kb + quad) ^ (d & 7)) * 8)));
      }
#pragma unroll
      for (int mi = 0; mi < 4; ++mi)
#pragma unroll
        for (int ni = 0; ni < 4; ++ni)
          acc[mi][ni] = __builtin_amdgcn_mfma_f32_16x16x32_bf16(av[mi], bv[ni], acc[mi][ni], 0, 0, 0);
    }
    __syncthreads();
  }

  if (do_sum) {
    rowsum += __shfl_xor(rowsum, 1, 64);          // pair threads share a row
    if ((tid & 1) == 0) s[(size_t)br * N_ + n0 + arow] = rowsum;
  }

  unsigned short* Pb = P + (size_t)br * (N_ * DE_);
#pragma unroll
  for (int mi = 0; mi < 4; ++mi)
#pragma unroll
    for (int t = 0; t < 4; ++t) {
      int row = n0 + wm * 64 + mi * 16 + quad * 4 + t;
#pragma unroll
      for (int ni = 0; ni < 4; ++ni) {
        int col = d0 + wn * 64 + ni * 16 + l16;
        Pb[(size_t)row * DE_ + col] = f2b(acc[mi][ni][t]);
      }
    }
}

// ---------------- stage 2: out[b] = P[b] @ Wn + spad @ Ub + bias ---------------
// 64x128 tile, K = 40 steps of 64 over (r,d) + 1 rank-R step. Both operands bf16
// via global_load_lds. 4 waves 2x2 (32x64 each).
__global__ void stage2_gemm(const unsigned short* __restrict__ P,
                            const unsigned short* __restrict__ Wn,
                            const unsigned short* __restrict__ spad,
                            const unsigned short* __restrict__ Ub,
                            const float* __restrict__ bias,
                            float* __restrict__ out) {
  __shared__ unsigned short Al[64 * 64];
  __shared__ unsigned short Bl[128 * 64];
  const int b  = blockIdx.x;
  const int n1 = blockIdx.y * 64;
  const int o0 = blockIdx.z * 128;
  const int tid  = threadIdx.x;
  const int lane = tid & 63;
  const int wave = tid >> 6;
  const int wm = wave >> 1, wn = wave & 1;
  const int quad = lane >> 4, l16 = lane & 15;

  f32x4 acc[2][4];
#pragma unroll
  for (int i = 0; i < 2; ++i)
#pragma unroll
    for (int j = 0; j < 4; ++j) acc[i][j] = f32x4{0.f, 0.f, 0.f, 0.f};

  for (int st = 0; st < 41; ++st) {
    const int r  = st >> 2;
    const int dk = (st & 3) * 64;
    // A tile: 64 rows (P rows n1.., k-chunk of 64) or spad on last step
#pragma unroll
    for (int it = 0; it < 2; ++it) {
      int rowblk = it * 32 + wave * 8;
      int rl = rowblk + (lane >> 3);
      int kc = (lane & 7) ^ (rl & 7);
      const unsigned short* gp = (st < 40)
          ? P + ((size_t)(b * R_ + r) * N_ + (n1 + rl)) * DE_ + dk + kc * 8
          : spad + ((size_t)b * N_ + (n1 + rl)) * 64 + kc * 8;
      gl_lds16(gp, Al + rowblk * 64);
    }
    // B tile: 128 rows (Wn rows o0.., d-chunk of 64) or Ub on last step
#pragma unroll
    for (int it = 0; it < 4; ++it) {
      int rowblk = it * 32 + wave * 8;
      int rl = rowblk + (lane >> 3);
      int kc = (lane & 7) ^ (rl & 7);
      const unsigned short* gp = (st < 40)
          ? Wn + ((size_t)r * DOUT_ + (o0 + rl)) * DE_ + dk + kc * 8
          : Ub + ((size_t)b * DOUT_ + (o0 + rl)) * 64 + kc * 8;
      gl_lds16(gp, Bl + rowblk * 64);
    }
    __syncthreads();
#pragma unroll
    for (int ks = 0; ks < 2; ++ks) {
      const int kb = ks * 4;
      v8bf av[2], bv[4];
#pragma unroll
      for (int mi = 0; mi < 2; ++mi) {
        int m = wm * 32 + mi * 16 + l16;
        av[mi] = us2bf(*(const v8us*)(Al + m * 64 + (((kb + quad) ^ (m & 7)) * 8)));
      }
#pragma unroll
      for (int ni = 0; ni < 4; ++ni) {
        int o = wn * 64 + ni * 16 + l16;
        bv[ni] = us2bf(*(const v8us*)(Bl + o * 64 + (((kb + quad) ^ (o & 7)) * 8)));
      }
#pragma unroll
      for (int mi = 0; mi < 2; ++mi)
#pragma unroll
        for (int ni = 0; ni < 4; ++ni)
          acc[mi][ni] = __builtin_amdgcn_mfma_f32_16x16x32_bf16(av[mi], bv[ni], acc[mi][ni], 0, 0, 0);
    }
    __syncthreads();
  }

  float* outb = out + (size_t)b * (N_ * DOUT_);
#pragma unroll
  for (int mi = 0; mi < 2; ++mi)
#pragma unroll
    for (int t = 0; t < 4; ++t) {
      int row = n1 + wm * 32 + mi * 16 + quad * 4 + t;
#pragma unroll
      for (int ni = 0; ni < 4; ++ni) {
        int col = o0 + wn * 64 + ni * 16 + l16;
        outb[(size_t)row * DOUT_ + col] = acc[mi][ni][t] + bias[col];
      }
    }
}

// ---------------- launch -------------------------------------------------------
extern "C" void kernel_launch(void* const* d_in, const int* in_sizes, int n_in,
                              void* d_out, int out_size, void* d_ws, size_t ws_size,
                              hipStream_t stream) {
  const float* node = (const float*)d_in[0];
  const float* rel  = (const float*)d_in[1];
  const float* adj  = (const float*)d_in[2];
  const float* W    = (const float*)d_in[3];
  const float* bias = (const float*)d_in[4];
  float* out = (float*)d_out;

  char* ws = (char*)d_ws;
  // layout (48.5 MB total):
  unsigned short* nodeT = (unsigned short*)(ws);                      // 4 MB
  unsigned short* Wn    = (unsigned short*)(ws + ((size_t)4  << 20)); // 1.25 MB
  unsigned short* P     = (unsigned short*)(ws + ((size_t)6  << 20)); // 40 MB
  float*          s     = (float*)         (ws + ((size_t)46 << 20)); // 0.31 MB
  unsigned short* spad  = (unsigned short*)(ws + ((size_t)47 << 20)); // 1 MB
  unsigned short* Ub    = (unsigned short*)(ws + ((size_t)48 << 20)); // 0.5 MB

  prep_nodeT<<<dim3(B_, N_ / 32, DE_ / 32), 256, 0, stream>>>(node, nodeT);
  prep_W<<<dim3((R_ * DOUT_ * DE_) / 256), 256, 0, stream>>>(W, Wn);
  prep_U<<<dim3((B_ * DOUT_ * 64) / 256), 256, 0, stream>>>(rel, W, Ub);
  stage1_gemm<<<dim3(B_ * R_, N_ / 128, DE_ / 128), 256, 0, stream>>>(adj, nodeT, P, s);
  prep_spad<<<dim3((B_ * N_ * 64) / 256), 256, 0, stream>>>(s, spad);
  stage2_gemm<<<dim3(B_, N_ / 64, DOUT_ / 128), 256, 0, stream>>>(P, Wn, spad, Ub, bias, out);
}

// Round 2
// 325.817 us; speedup vs baseline: 1.1246x; 1.1246x over previous
//
#include <hip/hip_runtime.h>
#include <stdint.h>

// Problem constants
#define B_     16
#define N_     512
#define R_     10
#define DE_    256
#define DR_    64
#define DOUT_  256
#define INDIM_ 3200   // (DE+DR)*R
#define BLK_   320    // DE+DR

typedef __bf16          v8bf  __attribute__((ext_vector_type(8)));
typedef unsigned short  v8us  __attribute__((ext_vector_type(8)));
typedef unsigned short  v4us  __attribute__((ext_vector_type(4)));
typedef float           f32x4 __attribute__((ext_vector_type(4)));

static __device__ __forceinline__ unsigned short f2b(float f) {
  union { float f; unsigned u; } c; c.f = f;
  unsigned r = c.u + 0x7FFFu + ((c.u >> 16) & 1u);   // RNE
  return (unsigned short)(r >> 16);
}

static __device__ __forceinline__ v8bf us2bf(v8us u) {
  union { v8us u; v8bf b; } c; c.u = u; return c.b;
}

// async global->LDS, 16B per lane; LDS dest = wave-uniform base + lane*16
static __device__ __forceinline__ void gl_lds16(const void* g, void* l) {
  __builtin_amdgcn_global_load_lds(
      (const __attribute__((address_space(1))) void*)g,
      (__attribute__((address_space(3))) void*)l, 16, 0, 0);
}

// ---------------- prep: node [b][m][d] f32 -> nodeT [b][d][m] bf16 -------------
__global__ void prep_nodeT(const float* __restrict__ nf, unsigned short* __restrict__ nodeT) {
  __shared__ float t[32][33];
  const int b = blockIdx.x, m0 = blockIdx.y * 32, d0 = blockIdx.z * 32;
  const int tid = threadIdx.x;
  const int c = tid & 31, rr = tid >> 5;
#pragma unroll
  for (int i = 0; i < 4; ++i) {
    int m = rr + i * 8;
    t[m][c] = nf[((size_t)b * N_ + (m0 + m)) * DE_ + d0 + c];
  }
  __syncthreads();
#pragma unroll
  for (int i = 0; i < 4; ++i) {
    int d = rr + i * 8;
    nodeT[((size_t)b * DE_ + (d0 + d)) * N_ + m0 + c] = f2b(t[c][d]);
  }
}

// ---------------- prep: W -> Wn [r][o][d] bf16 (node-part slice, d contiguous) --
__global__ void prep_W(const float* __restrict__ W, unsigned short* __restrict__ Wn) {
  int idx = blockIdx.x * 256 + threadIdx.x;        // < R*DOUT*DE = 655360
  int r = idx >> 16;                                // / (DOUT*DE)
  int o = (idx >> 8) & 255;
  int d = idx & 255;
  Wn[idx] = f2b(W[(size_t)o * INDIM_ + r * BLK_ + d]);
}

// ---------------- prep: U_bf [b][o][kk] = sum_dr rel[b,kk,dr]*W[o, kk*320+256+dr]
__global__ void prep_U(const float* __restrict__ rel, const float* __restrict__ W,
                       unsigned short* __restrict__ Ub) {
  int idx = blockIdx.x * 256 + threadIdx.x;        // < B*DOUT*64 = 262144
  int kk = idx & 63;
  int o  = (idx >> 6) & 255;
  int b  = idx >> 14;
  float v = 0.f;
  if (kk < R_) {
    const float* rp = rel + ((size_t)b * R_ + kk) * DR_;
    const float* wp = W + (size_t)o * INDIM_ + kk * BLK_ + DE_;
#pragma unroll 8
    for (int d = 0; d < DR_; ++d) v += rp[d] * wp[d];
  }
  Ub[idx] = f2b(v);
}

// ---------------- prep: spad [b][n][kk] = bf16(s[b][kk][n]) (kk<R else 0) -------
__global__ void prep_spad(const float* __restrict__ s, unsigned short* __restrict__ spad) {
  int idx = blockIdx.x * 256 + threadIdx.x;        // < B*N*64 = 524288
  int kk = idx & 63;
  int n  = (idx >> 6) & 511;
  int b  = idx >> 15;
  float v = (kk < R_) ? s[((size_t)b * R_ + kk) * N_ + n] : 0.f;
  spad[idx] = f2b(v);
}

// ---------------- out init: out[b,n,o] = bias[o] ------------------------------
__global__ void out_init(const float* __restrict__ bias, float* __restrict__ out) {
  int idx = blockIdx.x * 256 + threadIdx.x;        // 524288 threads x float4
  float4 bv = *(const float4*)(bias + (idx & 63) * 4);
  *(float4*)(out + (size_t)idx * 4) = bv;
}

// ---------------- stage 1: P[b,r] = adj[b,r] @ node[b]; s = rowsum(adj) --------
// 128(n) x 256(d = full DE) tile, BK=64, 512 threads / 8 waves in 2x4 grid
// (64x64 per wave). adj read ONCE (no d-split). A = adj fp32->bf16 inline with
// 16-lanes-per-row fully coalesced loads; rowsum accumulated in registers.
// B = nodeT bf16 via global_load_lds. XOR chunk swizzle on both LDS tiles.
__global__ void stage1_gemm(const float* __restrict__ adj,
                            const unsigned short* __restrict__ nodeT,
                            unsigned short* __restrict__ P,
                            float* __restrict__ s) {
  __shared__ unsigned short Al[128 * 64];   // 16 KB
  __shared__ unsigned short Bl[256 * 64];   // 32 KB
  const int br = blockIdx.x;           // b*R + r
  const int b  = br / R_;
  const int n0 = blockIdx.y * 128;
  const int tid  = threadIdx.x;        // 0..511
  const int lane = tid & 63;
  const int wave = tid >> 6;           // 0..7
  const int wm = wave >> 2, wn = wave & 3;
  const int quad = lane >> 4, l16 = lane & 15;

  const float* adjb = adj + (size_t)br * (N_ * N_);
  const unsigned short* nodeTb = nodeT + (size_t)b * (DE_ * N_);

  f32x4 acc[4][4];
#pragma unroll
  for (int i = 0; i < 4; ++i)
#pragma unroll
    for (int j = 0; j < 4; ++j) acc[i][j] = f32x4{0.f, 0.f, 0.f, 0.f};

  // A staging geometry: 16 lanes per row, contiguous 256B per row
  const int arow   = tid >> 4;         // 0..31 (+32*j)
  const int acol   = (tid & 15) * 4;   // float col within the 64-wide k-chunk
  const int achunk = (tid & 15) >> 1;  // logical 8-us chunk
  const int ahalf  = tid & 1;          // which 4-us half of the chunk
  float rsum[4] = {0.f, 0.f, 0.f, 0.f};

  for (int k0 = 0; k0 < N_; k0 += 64) {
    // B tile: nodeT rows 0..255 (full DE), cols k0..k0+63 (async, swizzled)
#pragma unroll
    for (int it = 0; it < 4; ++it) {
      int rowblk = it * 64 + wave * 8;            // wave-uniform
      int rl = rowblk + (lane >> 3);
      int kc = (lane & 7) ^ (rl & 7);             // logical chunk for my slot
      gl_lds16(nodeTb + (size_t)rl * N_ + k0 + kc * 8, Bl + rowblk * 64);
    }
    // A tile: adj rows n0..n0+127 fp32 -> bf16, register rowsum
#pragma unroll
    for (int j = 0; j < 4; ++j) {
      int row = arow + 32 * j;
      float4 x = *(const float4*)(adjb + (size_t)(n0 + row) * N_ + k0 + acol);
      rsum[j] += (x.x + x.y) + (x.z + x.w);
      v4us u;
      u[0] = f2b(x.x); u[1] = f2b(x.y); u[2] = f2b(x.z); u[3] = f2b(x.w);
      int cs = achunk ^ (row & 7);
      *(v4us*)(Al + row * 64 + cs * 8 + ahalf * 4) = u;
    }
    __syncthreads();
#pragma unroll
    for (int ks = 0; ks < 2; ++ks) {
      const int kb = ks * 4;
      v8bf av[4], bv[4];
#pragma unroll
      for (int mi = 0; mi < 4; ++mi) {
        int m = wm * 64 + mi * 16 + l16;
        av[mi] = us2bf(*(const v8us*)(Al + m * 64 + (((kb + quad) ^ (m & 7)) * 8)));
      }
#pragma unroll
      for (int ni = 0; ni < 4; ++ni) {
        int d = wn * 64 + ni * 16 + l16;
        bv[ni] = us2bf(*(const v8us*)(Bl + d * 64 + (((kb + quad) ^ (d & 7)) * 8)));
      }
#pragma unroll
      for (int mi = 0; mi < 4; ++mi)
#pragma unroll
        for (int ni = 0; ni < 4; ++ni)
          acc[mi][ni] = __builtin_amdgcn_mfma_f32_16x16x32_bf16(av[mi], bv[ni], acc[mi][ni], 0, 0, 0);
    }
    __syncthreads();
  }

  // rowsum: reduce across the 16 lanes sharing each row, write once
#pragma unroll
  for (int j = 0; j < 4; ++j) {
    float v = rsum[j];
    v += __shfl_xor(v, 1);
    v += __shfl_xor(v, 2);
    v += __shfl_xor(v, 4);
    v += __shfl_xor(v, 8);
    if ((tid & 15) == 0) s[(size_t)br * N_ + n0 + arow + 32 * j] = v;
  }

  unsigned short* Pb = P + (size_t)br * (N_ * DE_);
#pragma unroll
  for (int mi = 0; mi < 4; ++mi)
#pragma unroll
    for (int t = 0; t < 4; ++t) {
      int row = n0 + wm * 64 + mi * 16 + quad * 4 + t;
#pragma unroll
      for (int ni = 0; ni < 4; ++ni) {
        int col = wn * 64 + ni * 16 + l16;
        Pb[(size_t)row * DE_ + col] = f2b(acc[mi][ni][t]);
      }
    }
}

// ---------------- stage 2: out[b] += P[b] @ Wn (+ spad @ Ub) -------------------
// Split-K=2 over relations: half0 = r0..4 (20 steps), half1 = r5..9 + rank step
// (21 steps). 64x128 tile, 4 waves 2x2. fp32 atomicAdd onto bias-initialized out.
__global__ void stage2_gemm(const unsigned short* __restrict__ P,
                            const unsigned short* __restrict__ Wn,
                            const unsigned short* __restrict__ spad,
                            const unsigned short* __restrict__ Ub,
                            float* __restrict__ out) {
  __shared__ unsigned short Al[64 * 64];
  __shared__ unsigned short Bl[128 * 64];
  const int b  = blockIdx.x;
  const int n1 = blockIdx.y * 64;
  const int o0 = (blockIdx.z & 1) * 128;
  const int half = blockIdx.z >> 1;
  const int tid  = threadIdx.x;
  const int lane = tid & 63;
  const int wave = tid >> 6;
  const int wm = wave >> 1, wn = wave & 1;
  const int quad = lane >> 4, l16 = lane & 15;

  f32x4 acc[2][4];
#pragma unroll
  for (int i = 0; i < 2; ++i)
#pragma unroll
    for (int j = 0; j < 4; ++j) acc[i][j] = f32x4{0.f, 0.f, 0.f, 0.f};

  const int nst = 20 + half;                       // half1 carries the rank step
  for (int st = 0; st < nst; ++st) {
    const bool rnk = (st == 20);
    const int r  = half * 5 + (st >> 2);
    const int dk = (st & 3) * 64;
    // A tile: 64 rows (P rows n1.., k-chunk of 64) or spad on rank step
#pragma unroll
    for (int it = 0; it < 2; ++it) {
      int rowblk = it * 32 + wave * 8;
      int rl = rowblk + (lane >> 3);
      int kc = (lane & 7) ^ (rl & 7);
      const unsigned short* gp = rnk
          ? spad + ((size_t)b * N_ + (n1 + rl)) * 64 + kc * 8
          : P + ((size_t)(b * R_ + r) * N_ + (n1 + rl)) * DE_ + dk + kc * 8;
      gl_lds16(gp, Al + rowblk * 64);
    }
    // B tile: 128 rows (Wn rows o0.., d-chunk of 64) or Ub on rank step
#pragma unroll
    for (int it = 0; it < 4; ++it) {
      int rowblk = it * 32 + wave * 8;
      int rl = rowblk + (lane >> 3);
      int kc = (lane & 7) ^ (rl & 7);
      const unsigned short* gp = rnk
          ? Ub + ((size_t)b * DOUT_ + (o0 + rl)) * 64 + kc * 8
          : Wn + ((size_t)r * DOUT_ + (o0 + rl)) * DE_ + dk + kc * 8;
      gl_lds16(gp, Bl + rowblk * 64);
    }
    __syncthreads();
#pragma unroll
    for (int ks = 0; ks < 2; ++ks) {
      const int kb = ks * 4;
      v8bf av[2], bv[4];
#pragma unroll
      for (int mi = 0; mi < 2; ++mi) {
        int m = wm * 32 + mi * 16 + l16;
        av[mi] = us2bf(*(const v8us*)(Al + m * 64 + (((kb + quad) ^ (m & 7)) * 8)));
      }
#pragma unroll
      for (int ni = 0; ni < 4; ++ni) {
        int o = wn * 64 + ni * 16 + l16;
        bv[ni] = us2bf(*(const v8us*)(Bl + o * 64 + (((kb + quad) ^ (o & 7)) * 8)));
      }
#pragma unroll
      for (int mi = 0; mi < 2; ++mi)
#pragma unroll
        for (int ni = 0; ni < 4; ++ni)
          acc[mi][ni] = __builtin_amdgcn_mfma_f32_16x16x32_bf16(av[mi], bv[ni], acc[mi][ni], 0, 0, 0);
    }
    __syncthreads();
  }

  float* outb = out + (size_t)b * (N_ * DOUT_);
#pragma unroll
  for (int mi = 0; mi < 2; ++mi)
#pragma unroll
    for (int t = 0; t < 4; ++t) {
      int row = n1 + wm * 32 + mi * 16 + quad * 4 + t;
#pragma unroll
      for (int ni = 0; ni < 4; ++ni) {
        int col = o0 + wn * 64 + ni * 16 + l16;
        atomicAdd(outb + (size_t)row * DOUT_ + col, acc[mi][ni][t]);
      }
    }
}

// ---------------- launch -------------------------------------------------------
extern "C" void kernel_launch(void* const* d_in, const int* in_sizes, int n_in,
                              void* d_out, int out_size, void* d_ws, size_t ws_size,
                              hipStream_t stream) {
  const float* node = (const float*)d_in[0];
  const float* rel  = (const float*)d_in[1];
  const float* adj  = (const float*)d_in[2];
  const float* W    = (const float*)d_in[3];
  const float* bias = (const float*)d_in[4];
  float* out = (float*)d_out;

  char* ws = (char*)d_ws;
  // layout (48.5 MB total):
  unsigned short* nodeT = (unsigned short*)(ws);                      // 4 MB
  unsigned short* Wn    = (unsigned short*)(ws + ((size_t)4  << 20)); // 1.25 MB
  unsigned short* P     = (unsigned short*)(ws + ((size_t)6  << 20)); // 40 MB
  float*          s     = (float*)         (ws + ((size_t)46 << 20)); // 0.31 MB
  unsigned short* spad  = (unsigned short*)(ws + ((size_t)47 << 20)); // 1 MB
  unsigned short* Ub    = (unsigned short*)(ws + ((size_t)48 << 20)); // 0.5 MB

  prep_nodeT<<<dim3(B_, N_ / 32, DE_ / 32), 256, 0, stream>>>(node, nodeT);
  prep_W<<<dim3((R_ * DOUT_ * DE_) / 256), 256, 0, stream>>>(W, Wn);
  prep_U<<<dim3((B_ * DOUT_ * 64) / 256), 256, 0, stream>>>(rel, W, Ub);
  stage1_gemm<<<dim3(B_ * R_, N_ / 128), 512, 0, stream>>>(adj, nodeT, P, s);
  prep_spad<<<dim3((B_ * N_ * 64) / 256), 256, 0, stream>>>(s, spad);
  out_init<<<dim3((B_ * N_ * DOUT_ / 4) / 256), 256, 0, stream>>>(bias, out);
  stage2_gemm<<<dim3(B_, N_ / 64, 4), 256, 0, stream>>>(P, Wn, spad, Ub, out);
}